// Round 1
// baseline (20.453 us; speedup 1.0000x reference)
//
#include <hip/hip_runtime.h>

namespace {
constexpr int NB   = 16;   // batches
constexpr int NN   = 96;   // nodes
constexpr int NS   = 4;    // edge feature dim
constexpr int NFIN = 8;    // layer-1 input features
constexpr int NH   = 32;   // hidden
constexpr int NP   = 256;  // preference pairs
constexpr int NPB  = 8;    // nodes per block
constexpr int NCHUNK = NN / NPB;  // 12

// ---------------- Layer 1: x(8) -> h1(32) ----------------
__global__ __launch_bounds__(256) void k1_layer1(
    const float* __restrict__ x, const float* __restrict__ a,
    const float* __restrict__ e, const float* __restrict__ W1,
    const float* __restrict__ b1, const float* __restrict__ root1,
    const float* __restrict__ bias1, float* __restrict__ h1out)
{
  const int bb    = blockIdx.y;
  const int chunk = blockIdx.x;
  const int t     = threadIdx.x;
  const int g     = t >> 5;       // node group 0..7
  const int lane  = t & 31;
  const int gn    = chunk * NPB + g;

  __shared__ float  xf[NN][NFIN];
  __shared__ float  xmask[NN];
  __shared__ int    idxL[NPB][NN];
  __shared__ float  avalL[NPB][NN];
  __shared__ float  aeL[NPB][NN * NS];
  __shared__ float4 T1s[NPB][8];   // 32 scalars [s*8+f]
  __shared__ float4 U1s[NPB][2];   // 8 scalars

  // stage x (96 x 9)
  for (int j = t; j < NN * 9; j += 256) {
    int node = j / 9, ch = j - node * 9;
    float v = x[(bb * NN + node) * 9 + ch];
    if (ch < NFIN) xf[node][ch] = v; else xmask[node] = v;
  }

  // ballot-compact neighbor list for this group's node
  const float* arow = a + (size_t)(bb * NN + gn) * NN;
  const float* erow = e + (size_t)(bb * NN + gn) * NN * NS;
  int base = 0;
  for (int r = 0; r < 3; ++r) {
    int i = r * 32 + lane;
    float av = arow[i];
    unsigned long long bal = __ballot(av != 0.0f);
    unsigned int m = ((t & 63) < 32) ? (unsigned int)bal : (unsigned int)(bal >> 32);
    int pref = __popc(m & ((1u << lane) - 1u));
    if (av != 0.0f) {
      int slot = base + pref;
      idxL[g][slot]  = i;
      avalL[g][slot] = av;
      float4 e4 = *(const float4*)(erow + i * NS);
      aeL[g][slot * 4 + 0] = av * e4.x;
      aeL[g][slot * 4 + 1] = av * e4.y;
      aeL[g][slot * 4 + 2] = av * e4.z;
      aeL[g][slot * 4 + 3] = av * e4.w;
    }
    base += __popc(m);
  }
  const int cnt = base;
  __syncthreads();

  // sparse contraction: thread = (s, f)
  const int s = lane >> 3, f = lane & 7;
  float accT = 0.f, accU = 0.f;
  for (int j = 0; j < cnt; ++j) {
    int   idx = idxL[g][j];
    float av  = avalL[g][j];
    float ae  = aeL[g][j * 4 + s];
    float hv  = xf[idx][f];
    accT = fmaf(ae, hv, accT);
    accU = fmaf(av, hv, accU);
  }
  ((float*)T1s[g])[s * 8 + f] = accT;
  if (s == 0) ((float*)U1s[g])[f] = accU;
  __syncthreads();

  // epilogue: thread = c
  const int c = lane;
  float E = bias1[c];
  const float4* W1_4 = (const float4*)W1;   // (4,256) floats
  for (int ss = 0; ss < 4; ++ss)
    for (int f4 = 0; f4 < 2; ++f4) {
      float4 w  = W1_4[ss * 64 + c * 2 + f4];
      float4 tt = T1s[g][ss * 2 + f4];
      E = fmaf(w.x, tt.x, E); E = fmaf(w.y, tt.y, E);
      E = fmaf(w.z, tt.z, E); E = fmaf(w.w, tt.w, E);
    }
  const float4* b1_4 = (const float4*)b1;   // 256 floats
  for (int q = 0; q < 2; ++q) {
    float4 w = b1_4[c * 2 + q];
    float4 u = U1s[g][q];
    E = fmaf(w.x, u.x, E); E = fmaf(w.y, u.y, E);
    E = fmaf(w.z, u.z, E); E = fmaf(w.w, u.w, E);
  }
  for (int ff = 0; ff < NFIN; ++ff)
    E = fmaf(xf[gn][ff], root1[ff * NH + c], E);
  float hv = E * xmask[gn];
  h1out[(size_t)(bb * NN + gn) * NH + c] = hv > 0.f ? hv : 0.f;
}

// ---------------- Layer 2: h1(32) -> h2(32), partial pooling ----------------
__global__ __launch_bounds__(256) void k2_layer2(
    const float* __restrict__ x, const float* __restrict__ a,
    const float* __restrict__ e, const float* __restrict__ W2,
    const float* __restrict__ b2, const float* __restrict__ root2,
    const float* __restrict__ bias2, const float* __restrict__ h1,
    float* __restrict__ poolp)
{
  const int bb    = blockIdx.y;
  const int chunk = blockIdx.x;
  const int t     = threadIdx.x;
  const int g     = t >> 5;
  const int lane  = t & 31;
  const int gn    = chunk * NPB + g;

  __shared__ float4 h1s[NN * 8];       // h1[b] as float4 rows (12 KB)
  __shared__ int    idxL[NPB][NN];
  __shared__ float  avalL[NPB][NN];
  __shared__ float  aeL[NPB][NN * NS];
  __shared__ float4 T2s[NPB][32];      // [s*8+f4]
  __shared__ float4 U2s[NPB][8];
  __shared__ float  h2s[NPB][NH];
  __shared__ float  maskL[NPB];

  const float4* h1v = (const float4*)h1;
  for (int j = t; j < NN * 8; j += 256) h1s[j] = h1v[(size_t)bb * NN * 8 + j];
  if (lane == 0) maskL[g] = x[(size_t)(bb * NN + gn) * 9 + 8];

  const float* arow = a + (size_t)(bb * NN + gn) * NN;
  const float* erow = e + (size_t)(bb * NN + gn) * NN * NS;
  int base = 0;
  for (int r = 0; r < 3; ++r) {
    int i = r * 32 + lane;
    float av = arow[i];
    unsigned long long bal = __ballot(av != 0.0f);
    unsigned int m = ((t & 63) < 32) ? (unsigned int)bal : (unsigned int)(bal >> 32);
    int pref = __popc(m & ((1u << lane) - 1u));
    if (av != 0.0f) {
      int slot = base + pref;
      idxL[g][slot]  = i;
      avalL[g][slot] = av;
      float4 e4 = *(const float4*)(erow + i * NS);
      aeL[g][slot * 4 + 0] = av * e4.x;
      aeL[g][slot * 4 + 1] = av * e4.y;
      aeL[g][slot * 4 + 2] = av * e4.z;
      aeL[g][slot * 4 + 3] = av * e4.w;
    }
    base += __popc(m);
  }
  const int cnt = base;
  __syncthreads();

  // sparse contraction: thread = (s, f4), float4 accumulators over f
  const int s = lane >> 3, f4 = lane & 7;
  float4 accT = make_float4(0.f, 0.f, 0.f, 0.f);
  float4 accU = make_float4(0.f, 0.f, 0.f, 0.f);
  for (int j = 0; j < cnt; ++j) {
    int    idx = idxL[g][j];
    float  av  = avalL[g][j];
    float  ae  = aeL[g][j * 4 + s];
    float4 h4  = h1s[idx * 8 + f4];
    accT.x = fmaf(ae, h4.x, accT.x); accT.y = fmaf(ae, h4.y, accT.y);
    accT.z = fmaf(ae, h4.z, accT.z); accT.w = fmaf(ae, h4.w, accT.w);
    accU.x = fmaf(av, h4.x, accU.x); accU.y = fmaf(av, h4.y, accU.y);
    accU.z = fmaf(av, h4.z, accU.z); accU.w = fmaf(av, h4.w, accU.w);
  }
  T2s[g][s * 8 + f4] = accT;
  if (s == 0) U2s[g][f4] = accU;
  __syncthreads();

  // epilogue: thread = c
  const int c = lane;
  float E = bias2[c];
  const float4* W2_4 = (const float4*)W2;  // (4,1024) floats
  for (int ss = 0; ss < 4; ++ss)
    for (int q = 0; q < 8; ++q) {
      float4 w  = W2_4[ss * 256 + c * 8 + q];
      float4 tt = T2s[g][ss * 8 + q];
      E = fmaf(w.x, tt.x, E); E = fmaf(w.y, tt.y, E);
      E = fmaf(w.z, tt.z, E); E = fmaf(w.w, tt.w, E);
    }
  const float4* b2_4 = (const float4*)b2;  // 1024 floats
  for (int q = 0; q < 8; ++q) {
    float4 w = b2_4[c * 8 + q];
    float4 u = U2s[g][q];
    E = fmaf(w.x, u.x, E); E = fmaf(w.y, u.y, E);
    E = fmaf(w.z, u.z, E); E = fmaf(w.w, u.w, E);
  }
  for (int q = 0; q < 8; ++q) {
    float4 hh = h1s[gn * 8 + q];
    E = fmaf(hh.x, root2[(q * 4 + 0) * NH + c], E);
    E = fmaf(hh.y, root2[(q * 4 + 1) * NH + c], E);
    E = fmaf(hh.z, root2[(q * 4 + 2) * NH + c], E);
    E = fmaf(hh.w, root2[(q * 4 + 3) * NH + c], E);
  }
  float hv = E * maskL[g];
  h2s[g][c] = hv > 0.f ? hv : 0.f;
  __syncthreads();

  if (t < NH) {
    float p = 0.f;
    for (int n = 0; n < NPB; ++n) p += h2s[n][t];
    poolp[(size_t)(bb * NCHUNK + chunk) * NH + t] = p;
  }
}

// ---------------- Pool reduce + score + preference diffs ----------------
__global__ __launch_bounds__(512) void k3_score(
    const float* __restrict__ poolp, const float* __restrict__ Wd,
    const float* __restrict__ bd, const int* __restrict__ pa,
    const int* __restrict__ pb, float* __restrict__ out)
{
  __shared__ float scores[NB];
  const int t = threadIdx.x;
  const int bb = t >> 5, c = t & 31;
  float v = 0.f;
  for (int k = 0; k < NCHUNK; ++k) v += poolp[(bb * NCHUNK + k) * NH + c];
  v *= Wd[c];
  v += __shfl_xor(v, 16);
  v += __shfl_xor(v, 8);
  v += __shfl_xor(v, 4);
  v += __shfl_xor(v, 2);
  v += __shfl_xor(v, 1);
  if (c == 0) {
    float sc = v + bd[0];
    scores[bb] = sc > 0.f ? sc : 0.f;
  }
  __syncthreads();
  if (t < NP) out[t] = scores[pa[t]] - scores[pb[t]];
}

} // namespace

extern "C" void kernel_launch(void* const* d_in, const int* in_sizes, int n_in,
                              void* d_out, int out_size, void* d_ws, size_t ws_size,
                              hipStream_t stream) {
  const float* x     = (const float*)d_in[0];
  const float* a     = (const float*)d_in[1];
  const float* e     = (const float*)d_in[2];
  const int*   pa    = (const int*)d_in[3];
  const int*   pb    = (const int*)d_in[4];
  const float* W1    = (const float*)d_in[5];
  const float* b1    = (const float*)d_in[6];
  const float* root1 = (const float*)d_in[7];
  const float* bias1 = (const float*)d_in[8];
  const float* W2    = (const float*)d_in[9];
  const float* b2    = (const float*)d_in[10];
  const float* root2 = (const float*)d_in[11];
  const float* bias2 = (const float*)d_in[12];
  const float* Wd    = (const float*)d_in[13];
  const float* bd    = (const float*)d_in[14];

  float* h1    = (float*)d_ws;                 // 16*96*32 floats
  float* poolp = h1 + NB * NN * NH;            // 16*12*32 floats
  float* out   = (float*)d_out;                // 256 floats

  dim3 grid(NCHUNK, NB);
  k1_layer1<<<grid, 256, 0, stream>>>(x, a, e, W1, b1, root1, bias1, h1);
  k2_layer2<<<grid, 256, 0, stream>>>(x, a, e, W2, b2, root2, bias2, h1, poolp);
  k3_score<<<1, 512, 0, stream>>>(poolp, Wd, bd, pa, pb, out);
}